// Round 2
// baseline (944.056 us; speedup 1.0000x reference)
//
#include <hip/hip_runtime.h>
#include <hip/hip_bf16.h>

// FlowEmbedding (B=4, N=M=4096, C=64, S=32, mlp=[64,64,64]) — all-f32 I/O.
// Pipeline: copy pos1 | KNN top-32 | A/Cn factorized layer-0 | stats0 | bn0 |
//           gram0 (G0,r0) | bnW(W1) | gram1 (layer1 + G1,r1) | bnW(W2) |
//           final (layer1+layer2+maxpool -> out). ws use ~11 MB.

#define N_ 4096
#define S_ 32
#define PTOT 524288.0f   // B*N*S

typedef unsigned int u32;

// ---------------- copy pos1 (output 0 passthrough): 49152 f32 = 12288 uint4 -
__global__ void k_copy(const uint4* __restrict__ s, uint4* __restrict__ d){
  int i = blockIdx.x * 256 + threadIdx.x;   // grid 48 x 256 = 12288 exact
  d[i] = s[i];
}

// ---------------- KNN: one query per wave, lane-distributed sorted top-32 ----
__global__ __launch_bounds__(256) void k_knn(const float* __restrict__ pos1,
        const float* __restrict__ pos2, int* __restrict__ idxb){
  int b = blockIdx.y;
  int lane = threadIdx.x & 63;
  int n = blockIdx.x * 4 + (threadIdx.x >> 6);
  const float* p1 = pos1 + b * 3 * N_;
  const float* p2 = pos2 + b * 3 * N_;
  float qx = p1[n], qy = p1[N_ + n], qz = p1[2 * N_ + n];
  float v = 3.4e38f; int vi = 0;       // lane i<32 holds i-th smallest so far
  float w32 = 3.4e38f;                 // current worst (slot 31)
  for (int c0 = 0; c0 < N_; c0 += 64){
    int j = c0 + lane;
    float dx = p2[j] - qx;
    float dy = p2[N_ + j] - qy;
    float dz = p2[2 * N_ + j] - qz;
    float dsq = dx * dx + dy * dy + dz * dz;
    unsigned long long mask = __ballot(dsq < w32);
    while (mask){
      int s = __builtin_ctzll(mask); mask &= mask - 1;
      float xd = __shfl(dsq, s);
      int   xj = c0 + s;
      int rank = __popcll(__ballot(v < xd));   // insertion position (<=32)
      float pv = __shfl_up(v, 1);
      int   pi = __shfl_up(vi, 1);
      if (lane >= rank){
        if (lane == rank){ v = xd; vi = xj; }
        else             { v = pv; vi = pi; }
      }
      if (lane >= 32) v = 3.4e38f;             // keep dummy zone clean
      w32 = __shfl(v, 31);
    }
  }
  int best = __shfl(vi, 0);                    // nearest neighbor index
  if (lane < 32){
    int id = (v > 25.0f) ? best : vi;          // dist > RADIUS -> nearest
    idxb[(b * N_ + n) * S_ + lane] = id;
  }
}

// ---------------- layer-0 factorization: A (MODE=0) / Cn (MODE=1) -----------
// A[b,j,:]  = W0[:,0:3]*pos2[:,j] + W0[:,3:67]*feat2[:,j]
// Cn[b,n,:] = W0[:,67:131]*feat1[:,n] - W0[:,0:3]*pos1[:,n]
template<int MODE>
__global__ __launch_bounds__(256) void k_precomp(const float* __restrict__ posx,
        const float* __restrict__ featx, const float* __restrict__ W0,
        float* __restrict__ outp){
  __shared__ float Ws[67][65];
  __shared__ float Xs[67][65];
  int b = blockIdx.y, j0 = blockIdx.x * 64, t = threadIdx.x;
  for (int e = t; e < 67 * 64; e += 256){
    int r = e >> 6, o = e & 63;
    int wc = (MODE == 0) ? r : (r < 3 ? r : r + 64);
    Ws[r][o] = W0[o * 131 + wc];
    float x;
    if (r < 3){ x = posx[(b * 3 + r) * N_ + j0 + o]; if (MODE) x = -x; }
    else        x = featx[(b * 64 + (r - 3)) * N_ + j0 + o];
    Xs[r][o] = x;
  }
  __syncthreads();
  int og = t & 15, sl = t >> 4;
  float acc[4][4] = {};
  for (int r = 0; r < 67; ++r){
    float w0v = Ws[r][og*4+0], w1v = Ws[r][og*4+1], w2v = Ws[r][og*4+2], w3v = Ws[r][og*4+3];
    #pragma unroll
    for (int c = 0; c < 4; ++c){
      float xv = Xs[r][sl*4+c];
      acc[c][0] += xv*w0v; acc[c][1] += xv*w1v; acc[c][2] += xv*w2v; acc[c][3] += xv*w3v;
    }
  }
  #pragma unroll
  for (int c = 0; c < 4; ++c){
    float4 val; val.x = acc[c][0]; val.y = acc[c][1]; val.z = acc[c][2]; val.w = acc[c][3];
    *(float4*)&outp[((size_t)(b * N_ + j0 + sl*4 + c)) * 64 + og*4] = val;
  }
}

// ---------------- stats of h0 (pre-BN0): direct gather ----------------------
__global__ __launch_bounds__(256) void k_stats0(const int* __restrict__ idxb,
    const float* __restrict__ A, const float* __restrict__ Cn,
    float* __restrict__ sum0, float* __restrict__ sumsq0){
  int b = blockIdx.x >> 7, n0 = (blockIdx.x & 127) * 32;
  int c = threadIdx.x & 63, slq = threadIdx.x >> 6;
  float a1 = 0.f, a2 = 0.f;
  for (int q = 0; q < 32; ++q){
    int n = n0 + q;
    float cn = Cn[((size_t)(b * N_ + n)) * 64 + c];
    const int* ip = idxb + (b * N_ + n) * 32;
    for (int s = slq; s < 32; s += 4){
      int j = ip[s];
      float h = A[((size_t)(b * N_ + j)) * 64 + c] + cn;
      a1 += h; a2 += h * h;
    }
  }
  __shared__ float red[2][4][64];
  red[0][slq][c] = a1; red[1][slq][c] = a2;
  __syncthreads();
  if (threadIdx.x < 64){
    float s1 = red[0][0][c] + red[0][1][c] + red[0][2][c] + red[0][3][c];
    float s2 = red[1][0][c] + red[1][1][c] + red[1][2][c] + red[1][3][c];
    atomicAdd(&sum0[c], s1);
    atomicAdd(&sumsq0[c], s2);
  }
}

// ---------------- BN param kernels ------------------------------------------
__global__ void k_bn0(const float* sum0, const float* sumsq0, const float* g,
                      const float* bb, float* bnp){
  int c = threadIdx.x;
  float m = sum0[c] * (1.0f / PTOT);
  float v = sumsq0[c] * (1.0f / PTOT) - m * m;
  v = v > 0.f ? v : 0.f;
  float sc = g[c] * rsqrtf(v + 1e-5f);
  bnp[c] = sc; bnp[64 + c] = bb[c] - m * sc;
}

// stats of h = W*y from Gram: sum_p h[o] = W[o].r ; sum_p h[o]^2 = W[o] G W[o]^T
__global__ void k_bnW(const float* __restrict__ W, const float* __restrict__ r,
    const float* __restrict__ G, const float* g, const float* bb, float* bnp){
  int o = threadIdx.x;
  float mean = 0.f;
  for (int c = 0; c < 64; ++c) mean += W[o * 64 + c] * r[c];
  float qq = 0.f;
  for (int c = 0; c < 64; ++c){
    float wc = W[o * 64 + c];
    float t1 = 0.f;
    for (int d = 0; d < 64; ++d) t1 += G[c * 64 + d] * W[o * 64 + d];
    qq += wc * t1;
  }
  float m = mean * (1.0f / PTOT);
  float v = qq * (1.0f / PTOT) - m * m;
  v = v > 0.f ? v : 0.f;
  float sc = g[o] * rsqrtf(v + 1e-5f);
  bnp[o] = sc; bnp[64 + o] = bb[o] - m * sc;
}

// build one 64-column chunk of y0^T into LDS (columns = 2 queries x 32 s)
#define BUILD_YT(QEXPR)                                                      \
  {                                                                          \
    int q = (QEXPR);                                                         \
    int j = idx_s[q][p & 31];                                                \
    const float* ap = &A[((size_t)(b * N_ + j)) * 64 + cg * 16];             \
    _Pragma("unroll")                                                        \
    for (int k = 0; k < 16; k += 4){                                         \
      float4 av = *(const float4*)(ap + k);                                  \
      int cb = cg * 16 + k;                                                  \
      float h0v = av.x + Cn_s[q][cb+0];                                      \
      float h1v = av.y + Cn_s[q][cb+1];                                      \
      float h2v = av.z + Cn_s[q][cb+2];                                      \
      float h3v = av.w + Cn_s[q][cb+3];                                      \
      float y0v = sc0[cb+0]*h0v + sh0[cb+0]; yT[cb+0][p] = y0v > 0.f ? y0v : 0.f; \
      float y1v = sc0[cb+1]*h1v + sh0[cb+1]; yT[cb+1][p] = y1v > 0.f ? y1v : 0.f; \
      float y2v = sc0[cb+2]*h2v + sh0[cb+2]; yT[cb+2][p] = y2v > 0.f ? y2v : 0.f; \
      float y3v = sc0[cb+3]*h3v + sh0[cb+3]; yT[cb+3][p] = y3v > 0.f ? y3v : 0.f; \
    }                                                                        \
  }

// ---------------- gram0: G0 = sum y0 y0^T, r0 = sum y0 ----------------------
__global__ __launch_bounds__(256) void k_gram0(const int* __restrict__ idxb,
    const float* __restrict__ A, const float* __restrict__ Cn,
    const float* __restrict__ bnp0, float* __restrict__ G0, float* __restrict__ r0){
  __shared__ int   idx_s[64][32];
  __shared__ float Cn_s[64][64];
  __shared__ float sc0[64], sh0[64];
  __shared__ float yT[64][65];
  int b = blockIdx.y, n0 = blockIdx.x * 64, t = threadIdx.x;
  for (int e = t; e < 2048; e += 256) idx_s[e >> 5][e & 31] = idxb[(b * N_ + n0) * 32 + e];
  for (int e = t; e < 4096; e += 256) Cn_s[e >> 6][e & 63] = Cn[((size_t)(b * N_ + n0)) * 64 + e];
  if (t < 64){ sc0[t] = bnp0[t]; sh0[t] = bnp0[64 + t]; }
  int p = t & 63, cg = t >> 6;
  int slot = t >> 6, ti = (t & 63) & 7, tj = (t & 63) >> 3;
  float acc[8][8] = {};
  float rs = 0.f;
  __syncthreads();
  for (int ch = 0; ch < 32; ++ch){
    BUILD_YT(ch * 2 + (p >> 5))
    __syncthreads();
    #pragma unroll 2
    for (int pp = 0; pp < 16; ++pp){
      int p2 = slot * 16 + pp;
      float xi[8], xj[8];
      #pragma unroll
      for (int k = 0; k < 8; ++k){ xi[k] = yT[ti*8+k][p2]; xj[k] = yT[tj*8+k][p2]; }
      #pragma unroll
      for (int a = 0; a < 8; ++a)
        #pragma unroll
        for (int c = 0; c < 8; ++c) acc[a][c] += xi[a] * xj[c];
    }
    if (t < 64){
      #pragma unroll 4
      for (int p2 = 0; p2 < 64; ++p2) rs += yT[t][p2];
    }
    __syncthreads();
  }
  for (int ph = 0; ph < 4; ++ph){          // reduce acc across the 4 waves into yT
    if (slot == ph){
      #pragma unroll
      for (int a = 0; a < 8; ++a)
        #pragma unroll
        for (int c = 0; c < 8; ++c){
          float val = acc[a][c];
          if (ph) val += yT[ti*8+a][tj*8+c];
          yT[ti*8+a][tj*8+c] = val;
        }
    }
    __syncthreads();
  }
  for (int e = t; e < 4096; e += 256) atomicAdd(&G0[e], yT[e >> 6][e & 63]);
  if (t < 64) atomicAdd(&r0[t], rs);
}

// ---------------- gram1: h1 = W1 y0 ; y1 = relu(bn1) ; G1,r1 ----------------
__global__ __launch_bounds__(256) void k_gram1(const int* __restrict__ idxb,
    const float* __restrict__ A, const float* __restrict__ Cn,
    const float* __restrict__ bnp0, const float* __restrict__ bnp1,
    const float* __restrict__ W1, float* __restrict__ G1, float* __restrict__ r1o){
  __shared__ int   idx_s[32][32];
  __shared__ float Cn_s[32][64];
  __shared__ float sc0[64], sh0[64], sc1[64], sh1[64];
  __shared__ float W1f[64][65];            // W1f[c][o] = W1[o][c]
  __shared__ float yT[64][65];             // y0 tile, then overwritten by y1
  int b = blockIdx.y, n0 = blockIdx.x * 32, t = threadIdx.x;
  for (int e = t; e < 1024; e += 256) idx_s[e >> 5][e & 31] = idxb[(b * N_ + n0) * 32 + e];
  for (int e = t; e < 2048; e += 256) Cn_s[e >> 6][e & 63] = Cn[((size_t)(b * N_ + n0)) * 64 + e];
  for (int e = t; e < 4096; e += 256) W1f[e & 63][e >> 6] = W1[e];
  if (t < 64){ sc0[t]=bnp0[t]; sh0[t]=bnp0[64+t]; sc1[t]=bnp1[t]; sh1[t]=bnp1[64+t]; }
  int p = t & 63, cg = t >> 6;
  int slot = t >> 6, ti = (t & 63) & 7, tj = (t & 63) >> 3;
  int og = t & 15, sl = t >> 4;
  float acc[8][8] = {};
  float rs = 0.f;
  __syncthreads();
  for (int ch = 0; ch < 16; ++ch){
    BUILD_YT(ch * 2 + (p >> 5))
    __syncthreads();
    float ha[4][4] = {};
    for (int c = 0; c < 64; ++c){
      float w0v = W1f[c][og*4+0], w1v = W1f[c][og*4+1];
      float w2v = W1f[c][og*4+2], w3v = W1f[c][og*4+3];
      #pragma unroll
      for (int k = 0; k < 4; ++k){
        float xv = yT[c][sl*4+k];
        ha[0][k] += w0v*xv; ha[1][k] += w1v*xv; ha[2][k] += w2v*xv; ha[3][k] += w3v*xv;
      }
    }
    __syncthreads();                       // all y0 reads done -> safe to overwrite
    #pragma unroll
    for (int a = 0; a < 4; ++a){
      int o = og*4 + a;
      float s1 = sc1[o], b1v = sh1[o];
      #pragma unroll
      for (int k = 0; k < 4; ++k){
        float y = s1 * ha[a][k] + b1v;
        yT[o][sl*4+k] = y > 0.f ? y : 0.f;
      }
    }
    __syncthreads();
    #pragma unroll 2
    for (int pp = 0; pp < 16; ++pp){
      int p2 = slot * 16 + pp;
      float xi[8], xj[8];
      #pragma unroll
      for (int k = 0; k < 8; ++k){ xi[k] = yT[ti*8+k][p2]; xj[k] = yT[tj*8+k][p2]; }
      #pragma unroll
      for (int a = 0; a < 8; ++a)
        #pragma unroll
        for (int c = 0; c < 8; ++c) acc[a][c] += xi[a] * xj[c];
    }
    if (t < 64){
      #pragma unroll 4
      for (int p2 = 0; p2 < 64; ++p2) rs += yT[t][p2];
    }
    __syncthreads();                       // gram reads done -> next BUILD may write
  }
  for (int ph = 0; ph < 4; ++ph){
    if (slot == ph){
      #pragma unroll
      for (int a = 0; a < 8; ++a)
        #pragma unroll
        for (int c = 0; c < 8; ++c){
          float val = acc[a][c];
          if (ph) val += yT[ti*8+a][tj*8+c];
          yT[ti*8+a][tj*8+c] = val;
        }
    }
    __syncthreads();
  }
  for (int e = t; e < 4096; e += 256) atomicAdd(&G1[e], yT[e >> 6][e & 63]);
  if (t < 64) atomicAdd(&r1o[t], rs);
}

// ---------------- final: layer1 + layer2 + maxpool -> out --------------------
__global__ __launch_bounds__(256) void k_final(const int* __restrict__ idxb,
    const float* __restrict__ A, const float* __restrict__ Cn,
    const float* __restrict__ bnp0, const float* __restrict__ bnp1,
    const float* __restrict__ bnp2, const float* __restrict__ W1,
    const float* __restrict__ W2, float* __restrict__ outp){
  __shared__ int   idx_s[16][32];
  __shared__ float Cn_s[16][64];
  __shared__ float sc0[64], sh0[64], sc1[64], sh1[64], sc2[64], sh2[64];
  __shared__ float W1f[64][65];
  __shared__ float W2f[64][65];
  __shared__ float yT[64][65];             // y0 tile, then y1 tile
  __shared__ u32   omax[16][64];
  int b = blockIdx.y, n0 = blockIdx.x * 16, t = threadIdx.x;
  for (int e = t; e < 512; e += 256)  idx_s[e >> 5][e & 31] = idxb[(b * N_ + n0) * 32 + e];
  for (int e = t; e < 1024; e += 256) Cn_s[e >> 6][e & 63] = Cn[((size_t)(b * N_ + n0)) * 64 + e];
  for (int e = t; e < 4096; e += 256){ W1f[e & 63][e >> 6] = W1[e]; W2f[e & 63][e >> 6] = W2[e]; }
  for (int e = t; e < 1024; e += 256) ((u32*)omax)[e] = 0u;
  if (t < 64){ sc0[t]=bnp0[t]; sh0[t]=bnp0[64+t]; sc1[t]=bnp1[t]; sh1[t]=bnp1[64+t];
               sc2[t]=bnp2[t]; sh2[t]=bnp2[64+t]; }
  int p = t & 63, cg = t >> 6, og = t & 15, sl = t >> 4;
  __syncthreads();
  for (int ch = 0; ch < 8; ++ch){
    BUILD_YT(ch * 2 + (p >> 5))
    __syncthreads();
    float ha[4][4] = {};
    for (int c = 0; c < 64; ++c){
      float w0v = W1f[c][og*4+0], w1v = W1f[c][og*4+1];
      float w2v = W1f[c][og*4+2], w3v = W1f[c][og*4+3];
      #pragma unroll
      for (int k = 0; k < 4; ++k){
        float xv = yT[c][sl*4+k];
        ha[0][k] += w0v*xv; ha[1][k] += w1v*xv; ha[2][k] += w2v*xv; ha[3][k] += w3v*xv;
      }
    }
    __syncthreads();                       // y0 reads done
    #pragma unroll
    for (int a = 0; a < 4; ++a){
      int o = og*4 + a;
      float s1 = sc1[o], b1v = sh1[o];
      #pragma unroll
      for (int k = 0; k < 4; ++k){
        float y = s1 * ha[a][k] + b1v;
        yT[o][sl*4+k] = y > 0.f ? y : 0.f;
      }
    }
    __syncthreads();
    {
      float hb[4][4] = {};
      for (int c = 0; c < 64; ++c){
        float w0v = W2f[c][og*4+0], w1v = W2f[c][og*4+1];
        float w2v = W2f[c][og*4+2], w3v = W2f[c][og*4+3];
        #pragma unroll
        for (int k = 0; k < 4; ++k){
          float xv = yT[c][sl*4+k];
          hb[0][k] += w0v*xv; hb[1][k] += w1v*xv; hb[2][k] += w2v*xv; hb[3][k] += w3v*xv;
        }
      }
      int qloc = ch * 2 + (sl >> 3);
      #pragma unroll
      for (int a = 0; a < 4; ++a){
        int o = og*4 + a;
        float s2 = sc2[o], b2v = sh2[o];
        float mm = s2 * hb[a][0] + b2v;
        mm = fmaxf(mm, s2 * hb[a][1] + b2v);
        mm = fmaxf(mm, s2 * hb[a][2] + b2v);
        mm = fmaxf(mm, s2 * hb[a][3] + b2v);
        mm = mm > 0.f ? mm : 0.f;             // relu(max) == max(relu)
        atomicMax(&omax[qloc][o], __float_as_uint(mm));  // all >=0: uint order == float order
      }
    }
    __syncthreads();                       // y1 reads done -> next BUILD may write
  }
  for (int e = t; e < 1024; e += 256){
    int q = e & 15, o = e >> 4;
    outp[49152 + ((size_t)(b * 64 + o)) * N_ + n0 + q] = __uint_as_float(omax[q][o]);
  }
}

extern "C" void kernel_launch(void* const* d_in, const int* in_sizes, int n_in,
                              void* d_out, int out_size, void* d_ws, size_t ws_size,
                              hipStream_t stream){
  (void)in_sizes; (void)n_in; (void)out_size; (void)ws_size;
  const float* pos1 = (const float*)d_in[0];
  const float* pos2 = (const float*)d_in[1];
  const float* f1   = (const float*)d_in[2];
  const float* f2   = (const float*)d_in[3];
  const float* W0   = (const float*)d_in[4];
  const float* g0   = (const float*)d_in[5];
  const float* b0   = (const float*)d_in[6];
  const float* W1   = (const float*)d_in[7];
  const float* g1   = (const float*)d_in[8];
  const float* b1   = (const float*)d_in[9];
  const float* W2   = (const float*)d_in[10];
  const float* g2   = (const float*)d_in[11];
  const float* b2   = (const float*)d_in[12];

  char* ws = (char*)d_ws;
  int*   idxb = (int*)ws;                      // 2 MiB: idx[B][N][32]
  float* A    = (float*)(ws + (2u << 20));     // 4 MiB: A[b][j][64]
  float* Cn   = (float*)(ws + (6u << 20));     // 4 MiB: Cn[b][n][64]
  float* st   = (float*)(ws + (10u << 20));
  float* sum0   = st;              // 64
  float* sumsq0 = st + 64;         // 64
  float* r0     = st + 128;        // 64
  float* r1     = st + 192;        // 64
  float* G0     = st + 256;        // 4096
  float* G1     = st + 256 + 4096; // 4096
  float* bnp0   = st + 256 + 8192; // 128
  float* bnp1   = bnp0 + 128;
  float* bnp2   = bnp1 + 128;

  hipMemsetAsync(st, 0, (256 + 8192) * sizeof(float), stream);

  k_copy<<<dim3(48), 256, 0, stream>>>((const uint4*)pos1, (uint4*)d_out);
  k_knn<<<dim3(1024, 4), 256, 0, stream>>>(pos1, pos2, idxb);
  k_precomp<0><<<dim3(64, 4), 256, 0, stream>>>(pos2, f2, W0, A);
  k_precomp<1><<<dim3(64, 4), 256, 0, stream>>>(pos1, f1, W0, Cn);
  k_stats0<<<dim3(512), 256, 0, stream>>>(idxb, A, Cn, sum0, sumsq0);
  k_bn0<<<dim3(1), 64, 0, stream>>>(sum0, sumsq0, g0, b0, bnp0);
  k_gram0<<<dim3(64, 4), 256, 0, stream>>>(idxb, A, Cn, bnp0, G0, r0);
  k_bnW<<<dim3(1), 64, 0, stream>>>(W1, r0, G0, g1, b1, bnp1);
  k_gram1<<<dim3(128, 4), 256, 0, stream>>>(idxb, A, Cn, bnp0, bnp1, W1, G1, r1);
  k_bnW<<<dim3(1), 64, 0, stream>>>(W2, r1, G1, g2, b2, bnp2);
  k_final<<<dim3(256, 4), 256, 0, stream>>>(idxb, A, Cn, bnp0, bnp1, bnp2, W1, W2,
                                            (float*)d_out);
}

// Round 3
// 783.704 us; speedup vs baseline: 1.2046x; 1.2046x over previous
//
#include <hip/hip_runtime.h>
#include <hip/hip_bf16.h>

// FlowEmbedding (B=4, N=M=4096, C=64, S=32, mlp=[64,64,64]) — all-f32 I/O.
// R3: occupancy (16q blocks, no idx/Cn staging), bank-conflict fix (o=og+16a),
//     BN0 folded into A/Cn, sc1/sc2 folded into transposed weight copies.

#define N_ 4096
#define S_ 32
#define PTOT 524288.0f   // B*N*S

typedef unsigned short u16;
typedef unsigned int   u32;

__device__ __forceinline__ float b2f(u16 u){
  union { u32 i; float f; } x; x.i = ((u32)u) << 16; return x.f;
}
__device__ __forceinline__ u16 f2b(float f){
  __hip_bfloat16 h = __float2bfloat16(f);
  return *(u16*)&h;
}

// ---------------- copy pos1 (output 0 passthrough): 49152 f32 = 12288 uint4 -
__global__ void k_copy(const uint4* __restrict__ s, uint4* __restrict__ d){
  int i = blockIdx.x * 256 + threadIdx.x;   // grid 48 x 256 = 12288 exact
  d[i] = s[i];
}

// ---------------- KNN: one query per wave, lane-distributed sorted top-32 ----
__global__ __launch_bounds__(256) void k_knn(const float* __restrict__ pos1,
        const float* __restrict__ pos2, int* __restrict__ idxb){
  int b = blockIdx.y;
  int lane = threadIdx.x & 63;
  int n = blockIdx.x * 4 + (threadIdx.x >> 6);
  const float* p1 = pos1 + b * 3 * N_;
  const float* p2 = pos2 + b * 3 * N_;
  float qx = p1[n], qy = p1[N_ + n], qz = p1[2 * N_ + n];
  float v = 3.4e38f; int vi = 0;       // lane i<32 holds i-th smallest so far
  float w32 = 3.4e38f;                 // current worst (slot 31)
  for (int c0 = 0; c0 < N_; c0 += 64){
    int j = c0 + lane;
    float dx = p2[j] - qx;
    float dy = p2[N_ + j] - qy;
    float dz = p2[2 * N_ + j] - qz;
    float dsq = dx * dx + dy * dy + dz * dz;
    unsigned long long mask = __ballot(dsq < w32);
    while (mask){
      int s = __builtin_ctzll(mask); mask &= mask - 1;
      float xd = __shfl(dsq, s);
      int   xj = c0 + s;
      int rank = __popcll(__ballot(v < xd));   // insertion position (<=32)
      float pv = __shfl_up(v, 1);
      int   pi = __shfl_up(vi, 1);
      if (lane >= rank){
        if (lane == rank){ v = xd; vi = xj; }
        else             { v = pv; vi = pi; }
      }
      if (lane >= 32) v = 3.4e38f;             // keep dummy zone clean
      w32 = __shfl(v, 31);
    }
  }
  int best = __shfl(vi, 0);                    // nearest neighbor index
  if (lane < 32){
    int id = (v > 25.0f) ? best : vi;          // dist > RADIUS -> nearest
    idxb[(b * N_ + n) * S_ + lane] = id;
  }
}

// ---------------- layer-0 factorization: A (MODE=0) / Cn (MODE=1) -----------
// A[b,j,:]  = W0[:,0:3]*pos2[:,j] + W0[:,3:67]*feat2[:,j]
// Cn[b,n,:] = W0[:,67:131]*feat1[:,n] - W0[:,0:3]*pos1[:,n]
template<int MODE>
__global__ __launch_bounds__(256) void k_precomp(const float* __restrict__ posx,
        const float* __restrict__ featx, const float* __restrict__ W0,
        float* __restrict__ outp){
  __shared__ float Ws[67][65];
  __shared__ float Xs[67][65];
  int b = blockIdx.y, j0 = blockIdx.x * 64, t = threadIdx.x;
  for (int e = t; e < 67 * 64; e += 256){
    int r = e >> 6, o = e & 63;
    int wc = (MODE == 0) ? r : (r < 3 ? r : r + 64);
    Ws[r][o] = W0[o * 131 + wc];
    float x;
    if (r < 3){ x = posx[(b * 3 + r) * N_ + j0 + o]; if (MODE) x = -x; }
    else        x = featx[(b * 64 + (r - 3)) * N_ + j0 + o];
    Xs[r][o] = x;
  }
  __syncthreads();
  int og = t & 15, sl = t >> 4;
  float acc[4][4] = {};
  for (int r = 0; r < 67; ++r){
    float w0v = Ws[r][og*4+0], w1v = Ws[r][og*4+1], w2v = Ws[r][og*4+2], w3v = Ws[r][og*4+3];
    #pragma unroll
    for (int c = 0; c < 4; ++c){
      float xv = Xs[r][sl*4+c];
      acc[c][0] += xv*w0v; acc[c][1] += xv*w1v; acc[c][2] += xv*w2v; acc[c][3] += xv*w3v;
    }
  }
  #pragma unroll
  for (int c = 0; c < 4; ++c){
    float4 val; val.x = acc[c][0]; val.y = acc[c][1]; val.z = acc[c][2]; val.w = acc[c][3];
    *(float4*)&outp[((size_t)(b * N_ + j0 + sl*4 + c)) * 64 + og*4] = val;
  }
}

// ---------------- stats of h0 (pre-BN0): direct gather, float4 --------------
__global__ __launch_bounds__(256) void k_stats0(const int* __restrict__ idxb,
    const float* __restrict__ A, const float* __restrict__ Cn,
    float* __restrict__ sum0, float* __restrict__ sumsq0){
  int b = blockIdx.y, n0 = blockIdx.x * 32;
  int c4 = threadIdx.x & 15, sq = threadIdx.x >> 4;
  float4 a1 = {0,0,0,0}, a2 = {0,0,0,0};
  for (int q = 0; q < 32; ++q){
    int n = n0 + q;
    float4 cv = *(const float4*)&Cn[((size_t)(b * N_ + n)) * 64 + c4 * 4];
    const int* ip = idxb + (b * N_ + n) * 32;
    #pragma unroll
    for (int ss = 0; ss < 2; ++ss){
      int j = ip[sq + ss * 16];
      float4 av = *(const float4*)&A[((size_t)(b * N_ + j)) * 64 + c4 * 4];
      float h0 = av.x + cv.x, h1 = av.y + cv.y, h2 = av.z + cv.z, h3 = av.w + cv.w;
      a1.x += h0; a1.y += h1; a1.z += h2; a1.w += h3;
      a2.x += h0*h0; a2.y += h1*h1; a2.z += h2*h2; a2.w += h3*h3;
    }
  }
  __shared__ float red1[16][64];
  __shared__ float red2[16][64];
  *(float4*)&red1[sq][c4*4] = a1;
  *(float4*)&red2[sq][c4*4] = a2;
  __syncthreads();
  int t = threadIdx.x;
  if (t < 64){
    float s1 = 0.f, s2 = 0.f;
    #pragma unroll
    for (int k = 0; k < 16; ++k){ s1 += red1[k][t]; s2 += red2[k][t]; }
    atomicAdd(&sum0[t], s1);
    atomicAdd(&sumsq0[t], s2);
  }
}

// ---------------- BN param kernels ------------------------------------------
__global__ void k_bn0(const float* sum0, const float* sumsq0, const float* g,
                      const float* bb, float* bnp){
  int c = threadIdx.x;
  float m = sum0[c] * (1.0f / PTOT);
  float v = sumsq0[c] * (1.0f / PTOT) - m * m;
  v = v > 0.f ? v : 0.f;
  float sc = g[c] * rsqrtf(v + 1e-5f);
  bnp[c] = sc; bnp[64 + c] = bb[c] - m * sc;
}

// stats of h = W*y from Gram; also emits transposed, sc-folded weight copy.
// BF16OUT=0: Wt is float[64][64] (Wt[c][o] = sc[o]*W[o][c])
// BF16OUT=1: Wt is u16 bf16 [64][64]
template<int BF16OUT>
__global__ void k_bnW(const float* __restrict__ W, const float* __restrict__ r,
    const float* __restrict__ G, const float* g, const float* bb, float* bnp,
    void* __restrict__ Wt){
  int o = threadIdx.x;
  float mean = 0.f;
  for (int c = 0; c < 64; ++c) mean += W[o * 64 + c] * r[c];
  float qq = 0.f;
  for (int c = 0; c < 64; ++c){
    float wc = W[o * 64 + c];
    float t1 = 0.f;
    for (int d = 0; d < 64; ++d) t1 += G[c * 64 + d] * W[o * 64 + d];
    qq += wc * t1;
  }
  float m = mean * (1.0f / PTOT);
  float v = qq * (1.0f / PTOT) - m * m;
  v = v > 0.f ? v : 0.f;
  float sc = g[o] * rsqrtf(v + 1e-5f);
  bnp[o] = sc; bnp[64 + o] = bb[o] - m * sc;
  if (BF16OUT){
    u16* wt = (u16*)Wt;
    for (int c = 0; c < 64; ++c) wt[c * 64 + o] = f2b(sc * W[o * 64 + c]);
  } else {
    float* wt = (float*)Wt;
    for (int c = 0; c < 64; ++c) wt[c * 64 + o] = sc * W[o * 64 + c];
  }
}

// ---------------- fold BN0 into A (MODE=0) / Cn (MODE=1), in place ----------
template<int MODE>
__global__ void k_scaleAC(float* __restrict__ X, const float* __restrict__ bnp){
  int i = blockIdx.x * 256 + threadIdx.x;   // float4 index; grid 1024 x 256
  float4 v = ((float4*)X)[i];
  int c4 = i & 15;
  float4 sc = *(const float4*)&bnp[c4 * 4];
  if (MODE == 0){
    v.x *= sc.x; v.y *= sc.y; v.z *= sc.z; v.w *= sc.w;
  } else {
    float4 sh = *(const float4*)&bnp[64 + c4 * 4];
    v.x = v.x * sc.x + sh.x; v.y = v.y * sc.y + sh.y;
    v.z = v.z * sc.z + sh.z; v.w = v.w * sc.w + sh.w;
  }
  ((float4*)X)[i] = v;
}

// build one 64-col chunk of y0^T into LDS; A/Cn pre-folded: y0 = relu(A'+Cn')
#define BUILD_YT(CH)                                                          \
  {                                                                           \
    int nq = n0 + (CH) * 2 + (p >> 5);                                        \
    int jj = idxb[((size_t)(b * N_ + nq)) * 32 + (p & 31)];                   \
    const float* ap = &A[((size_t)(b * N_ + jj)) * 64 + cg * 16];             \
    const float* cp = &Cn[((size_t)(b * N_ + nq)) * 64 + cg * 16];            \
    _Pragma("unroll")                                                         \
    for (int kk = 0; kk < 16; kk += 4){                                       \
      float4 av = *(const float4*)(ap + kk);                                  \
      float4 cv = *(const float4*)(cp + kk);                                  \
      int cb = cg * 16 + kk;                                                  \
      float y0v = av.x + cv.x; yT[cb+0][p] = y0v > 0.f ? y0v : 0.f;           \
      float y1v = av.y + cv.y; yT[cb+1][p] = y1v > 0.f ? y1v : 0.f;           \
      float y2v = av.z + cv.z; yT[cb+2][p] = y2v > 0.f ? y2v : 0.f;           \
      float y3v = av.w + cv.w; yT[cb+3][p] = y3v > 0.f ? y3v : 0.f;           \
    }                                                                         \
  }

#define GRAM_ACC                                                              \
  _Pragma("unroll 2")                                                         \
  for (int pp = 0; pp < 16; ++pp){                                            \
    int p2 = slot * 16 + pp;                                                  \
    float xi[8], xj[8];                                                       \
    _Pragma("unroll")                                                         \
    for (int k2 = 0; k2 < 8; ++k2){ xi[k2] = yT[ti*8+k2][p2]; xj[k2] = yT[tj*8+k2][p2]; } \
    _Pragma("unroll")                                                         \
    for (int a2 = 0; a2 < 8; ++a2)                                            \
      _Pragma("unroll")                                                       \
      for (int c2 = 0; c2 < 8; ++c2) acc[a2][c2] += xi[a2] * xj[c2];          \
  }

#define GRAM_OUT(GPTR)                                                        \
  for (int ph = 0; ph < 4; ++ph){                                             \
    if (slot == ph){                                                          \
      _Pragma("unroll")                                                       \
      for (int a2 = 0; a2 < 8; ++a2)                                          \
        _Pragma("unroll")                                                     \
        for (int c2 = 0; c2 < 8; ++c2){                                       \
          float val = acc[a2][c2];                                            \
          if (ph) val += yT[ti*8+a2][tj*8+c2];                                \
          yT[ti*8+a2][tj*8+c2] = val;                                         \
        }                                                                     \
    }                                                                         \
    __syncthreads();                                                          \
  }                                                                           \
  for (int e = t; e < 4096; e += 256) atomicAdd(&(GPTR)[e], yT[e >> 6][e & 63]);

// ---------------- gram0: G0 = sum y0 y0^T, r0 = sum y0 ----------------------
__global__ __launch_bounds__(256) void k_gram0(const int* __restrict__ idxb,
    const float* __restrict__ A, const float* __restrict__ Cn,
    float* __restrict__ G0, float* __restrict__ r0){
  __shared__ float yT[64][65];
  int b = blockIdx.y, n0 = blockIdx.x * 16, t = threadIdx.x;
  int p = t & 63, cg = t >> 6;
  int slot = t >> 6, ti = (t & 63) & 7, tj = (t & 63) >> 3;
  float acc[8][8] = {};
  float rs = 0.f;
  for (int ch = 0; ch < 8; ++ch){
    BUILD_YT(ch)
    __syncthreads();
    GRAM_ACC
    if (t < 64){
      #pragma unroll 4
      for (int p2 = 0; p2 < 64; ++p2) rs += yT[t][p2];
    }
    __syncthreads();
  }
  GRAM_OUT(G0)
  if (t < 64) atomicAdd(&r0[t], rs);
}

// ---------------- gram1: y1 = relu(W1s*y0 + sh1) ; G1, r1 -------------------
__global__ __launch_bounds__(256) void k_gram1(const int* __restrict__ idxb,
    const float* __restrict__ A, const float* __restrict__ Cn,
    const float* __restrict__ W1t, const float* __restrict__ bnp1,
    float* __restrict__ G1, float* __restrict__ r1o){
  __shared__ float W1s[64][64];    // W1s[c][o], sc1 folded
  __shared__ float yT[64][65];
  __shared__ float sh1[64];
  __shared__ float r_s[64];
  int b = blockIdx.y, n0 = blockIdx.x * 16, t = threadIdx.x;
  for (int e = t; e < 4096; e += 256) ((float*)W1s)[e] = W1t[e];
  if (t < 64){ sh1[t] = bnp1[64 + t]; r_s[t] = 0.f; }
  int p = t & 63, cg = t >> 6;
  int slot = t >> 6, ti = (t & 63) & 7, tj = (t & 63) >> 3;
  int og = t & 15, sl = t >> 4;
  float acc[8][8] = {};
  float rs4[4] = {0.f, 0.f, 0.f, 0.f};
  __syncthreads();
  for (int ch = 0; ch < 8; ++ch){
    BUILD_YT(ch)
    __syncthreads();
    float ha[4][4] = {};
    for (int c = 0; c < 64; ++c){
      float w0v = W1s[c][og], w1v = W1s[c][og+16], w2v = W1s[c][og+32], w3v = W1s[c][og+48];
      #pragma unroll
      for (int k = 0; k < 4; ++k){
        float xv = yT[c][sl*4+k];
        ha[0][k] += w0v*xv; ha[1][k] += w1v*xv; ha[2][k] += w2v*xv; ha[3][k] += w3v*xv;
      }
    }
    __syncthreads();                       // y0 reads done -> overwrite
    #pragma unroll
    for (int a = 0; a < 4; ++a){
      int o = og + 16*a;
      float bv = sh1[o];
      #pragma unroll
      for (int k = 0; k < 4; ++k){
        float y = ha[a][k] + bv;
        y = y > 0.f ? y : 0.f;
        yT[o][sl*4+k] = y;
        rs4[a] += y;
      }
    }
    __syncthreads();
    GRAM_ACC
    __syncthreads();
  }
  GRAM_OUT(G1)
  #pragma unroll
  for (int a = 0; a < 4; ++a) atomicAdd(&r_s[og + 16*a], rs4[a]);
  __syncthreads();
  if (t < 64) atomicAdd(&r1o[t], r_s[t]);
}

// ---------------- final: layer1 + layer2 + maxpool -> out --------------------
__global__ __launch_bounds__(256) void k_final(const int* __restrict__ idxb,
    const float* __restrict__ A, const float* __restrict__ Cn,
    const float* __restrict__ W1t, const u16* __restrict__ W2u,
    const float* __restrict__ bnp1, const float* __restrict__ bnp2,
    float* __restrict__ outp){
  __shared__ float W1s[64][64];    // f32, sc1 folded
  __shared__ u16   W2s[64][64];    // bf16, sc2 folded
  __shared__ float yT[64][65];
  __shared__ float sh1[64], sh2[64];
  __shared__ u32   omax[16][64];
  int b = blockIdx.y, n0 = blockIdx.x * 16, t = threadIdx.x;
  for (int e = t; e < 4096; e += 256){ ((float*)W1s)[e] = W1t[e]; ((u16*)W2s)[e] = W2u[e]; }
  for (int e = t; e < 1024; e += 256) ((u32*)omax)[e] = 0u;
  if (t < 64){ sh1[t] = bnp1[64 + t]; sh2[t] = bnp2[64 + t]; }
  int p = t & 63, cg = t >> 6, og = t & 15, sl = t >> 4;
  __syncthreads();
  for (int ch = 0; ch < 8; ++ch){
    BUILD_YT(ch)
    __syncthreads();
    float ha[4][4] = {};
    for (int c = 0; c < 64; ++c){
      float w0v = W1s[c][og], w1v = W1s[c][og+16], w2v = W1s[c][og+32], w3v = W1s[c][og+48];
      #pragma unroll
      for (int k = 0; k < 4; ++k){
        float xv = yT[c][sl*4+k];
        ha[0][k] += w0v*xv; ha[1][k] += w1v*xv; ha[2][k] += w2v*xv; ha[3][k] += w3v*xv;
      }
    }
    __syncthreads();                       // y0 reads done
    #pragma unroll
    for (int a = 0; a < 4; ++a){
      int o = og + 16*a;
      float bv = sh1[o];
      #pragma unroll
      for (int k = 0; k < 4; ++k){
        float y = ha[a][k] + bv;
        yT[o][sl*4+k] = y > 0.f ? y : 0.f;
      }
    }
    __syncthreads();
    {
      float hb[4][4] = {};
      for (int c = 0; c < 64; ++c){
        float w0v = b2f(W2s[c][og]),    w1v = b2f(W2s[c][og+16]);
        float w2v = b2f(W2s[c][og+32]), w3v = b2f(W2s[c][og+48]);
        #pragma unroll
        for (int k = 0; k < 4; ++k){
          float xv = yT[c][sl*4+k];
          hb[0][k] += w0v*xv; hb[1][k] += w1v*xv; hb[2][k] += w2v*xv; hb[3][k] += w3v*xv;
        }
      }
      int qloc = ch * 2 + (sl >> 3);
      #pragma unroll
      for (int a = 0; a < 4; ++a){
        int o = og + 16*a;
        float bv = sh2[o];
        float mm = hb[a][0] + bv;
        mm = fmaxf(mm, hb[a][1] + bv);
        mm = fmaxf(mm, hb[a][2] + bv);
        mm = fmaxf(mm, hb[a][3] + bv);
        mm = mm > 0.f ? mm : 0.f;             // relu(max) == max(relu)
        atomicMax(&omax[qloc][o], __float_as_uint(mm));  // all >=0
      }
    }
    __syncthreads();                       // y1 reads done -> next BUILD may write
  }
  for (int e = t; e < 1024; e += 256){
    int q = e & 15, o = e >> 4;
    outp[49152 + ((size_t)(b * 64 + o)) * N_ + n0 + q] = __uint_as_float(omax[q][o]);
  }
}

extern "C" void kernel_launch(void* const* d_in, const int* in_sizes, int n_in,
                              void* d_out, int out_size, void* d_ws, size_t ws_size,
                              hipStream_t stream){
  (void)in_sizes; (void)n_in; (void)out_size; (void)ws_size;
  const float* pos1 = (const float*)d_in[0];
  const float* pos2 = (const float*)d_in[1];
  const float* f1   = (const float*)d_in[2];
  const float* f2   = (const float*)d_in[3];
  const float* W0   = (const float*)d_in[4];
  const float* g0   = (const float*)d_in[5];
  const float* b0   = (const float*)d_in[6];
  const float* W1   = (const float*)d_in[7];
  const float* g1   = (const float*)d_in[8];
  const float* b1   = (const float*)d_in[9];
  const float* W2   = (const float*)d_in[10];
  const float* g2   = (const float*)d_in[11];
  const float* b2   = (const float*)d_in[12];

  char* ws = (char*)d_ws;
  int*   idxb = (int*)ws;                        // 2 MiB: idx[B][N][32]
  float* A    = (float*)(ws + (2u << 20));       // 4 MiB: A[b][j][64]
  float* Cn   = (float*)(ws + (6u << 20));       // 4 MiB: Cn[b][n][64]
  float* W1t  = (float*)(ws + (10u << 20));      // 16 KiB f32 [c][o]
  u16*   W2u  = (u16*)  (ws + (10u << 20) + (16u << 10)); // 8 KiB bf16 [c][o]
  float* st   = (float*)(ws + (10u << 20) + (32u << 10));
  float* sum0   = st;              // 64
  float* sumsq0 = st + 64;         // 64
  float* r0     = st + 128;        // 64
  float* r1     = st + 192;        // 64
  float* G0     = st + 256;        // 4096
  float* G1     = st + 256 + 4096; // 4096
  float* bnp0   = st + 256 + 8192; // 128
  float* bnp1   = bnp0 + 128;
  float* bnp2   = bnp1 + 128;

  hipMemsetAsync(st, 0, (256 + 8192) * sizeof(float), stream);

  k_copy<<<dim3(48), 256, 0, stream>>>((const uint4*)pos1, (uint4*)d_out);
  k_knn<<<dim3(1024, 4), 256, 0, stream>>>(pos1, pos2, idxb);
  k_precomp<0><<<dim3(64, 4), 256, 0, stream>>>(pos2, f2, W0, A);
  k_precomp<1><<<dim3(64, 4), 256, 0, stream>>>(pos1, f1, W0, Cn);
  k_stats0<<<dim3(128, 4), 256, 0, stream>>>(idxb, A, Cn, sum0, sumsq0);
  k_bn0<<<dim3(1), 64, 0, stream>>>(sum0, sumsq0, g0, b0, bnp0);
  k_scaleAC<0><<<dim3(1024), 256, 0, stream>>>(A, bnp0);
  k_scaleAC<1><<<dim3(1024), 256, 0, stream>>>(Cn, bnp0);
  k_gram0<<<dim3(256, 4), 256, 0, stream>>>(idxb, A, Cn, G0, r0);
  k_bnW<0><<<dim3(1), 64, 0, stream>>>(W1, r0, G0, g1, b1, bnp1, (void*)W1t);
  k_gram1<<<dim3(256, 4), 256, 0, stream>>>(idxb, A, Cn, W1t, bnp1, G1, r1);
  k_bnW<1><<<dim3(1), 64, 0, stream>>>(W2, r1, G1, g2, b2, bnp2, (void*)W2u);
  k_final<<<dim3(256, 4), 256, 0, stream>>>(idxb, A, Cn, W1t, W2u, bnp1, bnp2,
                                            (float*)d_out);
}